// Round 1
// baseline (5845.573 us; speedup 1.0000x reference)
//
#include <hip/hip_runtime.h>
#include <hip/hip_bf16.h>

// Problem constants
#define NB 64
#define NT 512
#define NBT 32768      // NB*NT
#define NE 160
#define NV 16
#define NH 160
#define LNEPS 1e-5f

// d_out layout: temporal_ctx [B,T,H] | sparse_weights [B,T,1,V] | static_gate [B,T,V]
#define TC_OFF 0
#define SW_OFF 5242880
#define SG_OFF 5767168

// workspace layout (bytes)
// trws   : bf16 transformed, [V][BT][H] = 16*32768*160*2 = 167,772,160
// W1p    : f32 permuted fl_W1  [v][h][160]  = 1,638,400
// Wskp   : f32 permuted fl_Wskip [v][h][16] = 163,840
// ctxw   : f32 [B][H] = 40,960
#define WS_W1P_OFF  167772160ull
#define WS_WSKP_OFF (WS_W1P_OFF + 1638400ull)
#define WS_CTX_OFF  (WS_WSKP_OFF + 163840ull)

__device__ __forceinline__ float eluf(float x)  { return x > 0.f ? x : expm1f(x); }
__device__ __forceinline__ float sigmf(float x) { return 1.f / (1.f + expf(-x)); }

// One 64x32-column GEMM pass over K=160 from LDS A [64][161] and LDS W chunk [160][36].
// Thread owns rows {r2, r2+32} and cols {cg*4..cg*4+3} within the chunk.
__device__ __forceinline__ void gemm_pass(const float (*A)[161], const float (*W)[36],
                                          int r2, int cg, float* a0, float* a1)
{
#pragma unroll 4
  for (int k = 0; k < 160; ++k) {
    float x0 = A[r2][k];
    float x1 = A[r2 + 32][k];
    const float4 b = *(const float4*)&W[k][cg * 4];
    a0[0] += x0 * b.x; a0[1] += x0 * b.y; a0[2] += x0 * b.z; a0[3] += x0 * b.w;
    a1[0] += x1 * b.x; a1[1] += x1 * b.y; a1[2] += x1 * b.z; a1[3] += x1 * b.w;
  }
}

__device__ __forceinline__ void stage_w32(float (*W)[36], const float* __restrict__ src,
                                          int nc, int tid)
{
  // stage src[k][nc*32 + c] (ld=160) into W[k][c], k<160, c<32
  for (int i = tid; i < 160 * 32; i += 256) {
    int k = i >> 5, c = i & 31;
    W[k][c] = src[(size_t)k * 160 + nc * 32 + c];
  }
}

// ---------------- Kernel 1: per-variable GRN ----------------
// grid (16 v  [fastest], 512 row tiles), block 256
__global__ __launch_bounds__(256) void k_var_grn(
    const float* __restrict__ emb,
    const float* __restrict__ sW1, const float* __restrict__ sb1,
    const float* __restrict__ sW2, const float* __restrict__ sb2,
    const float* __restrict__ sWg, const float* __restrict__ sbg,
    const float* __restrict__ sWv, const float* __restrict__ sbv,
    const float* __restrict__ slns, const float* __restrict__ slnb,
    __hip_bfloat16* __restrict__ trws)
{
  __shared__ __align__(16) float Xs[64][161];
  __shared__ __align__(16) float Hs[64][161];
  __shared__ __align__(16) float Ws[160][36];
  __shared__ float redm[64];
  __shared__ float redr[64];

  const int tid  = threadIdx.x;
  const int v    = blockIdx.x;        // 0..15
  const int row0 = blockIdx.y * 64;   // bt tile start
  const int r2 = tid & 31, cg = tid >> 5;

  // stage x_v tile: Xs[r][e] = emb[(row0+r)*E*V + e*V + v]
  for (int i = tid; i < 64 * 160; i += 256) {
    int r = i / 160, e = i - r * 160;
    Xs[r][e] = emb[(size_t)(row0 + r) * 2560 + e * 16 + v];
  }
  __syncthreads();

  const size_t wvoff = (size_t)v * 160 * 160;

  // ---- layer 1: Hs = elu(Xs @ W1 + b1) ----
  for (int nc = 0; nc < 5; ++nc) {
    stage_w32(Ws, sW1 + wvoff, nc, tid);
    __syncthreads();
    float a0[4] = {0, 0, 0, 0}, a1[4] = {0, 0, 0, 0};
    gemm_pass(Xs, Ws, r2, cg, a0, a1);
    const int col = nc * 32 + cg * 4;
#pragma unroll
    for (int j = 0; j < 4; ++j) {
      float bb = sb1[v * 160 + col + j];
      Hs[r2][col + j]      = eluf(a0[j] + bb);
      Hs[r2 + 32][col + j] = eluf(a1[j] + bb);
    }
    __syncthreads();
  }

  // ---- layer 2: h2 = Hs @ W2 + b2 (accumulate all chunks, then overwrite Hs) ----
  float h0[5][4], h1[5][4];
#pragma unroll
  for (int nc = 0; nc < 5; ++nc)
#pragma unroll
    for (int j = 0; j < 4; ++j) { h0[nc][j] = 0.f; h1[nc][j] = 0.f; }

  for (int nc = 0; nc < 5; ++nc) {
    stage_w32(Ws, sW2 + wvoff, nc, tid);
    __syncthreads();
    gemm_pass(Hs, Ws, r2, cg, h0[nc], h1[nc]);
    __syncthreads();
  }
#pragma unroll
  for (int nc = 0; nc < 5; ++nc) {
    const int col = nc * 32 + cg * 4;
#pragma unroll
    for (int j = 0; j < 4; ++j) {
      float bb = sb2[v * 160 + col + j];
      Hs[r2][col + j]      = h0[nc][j] + bb;
      Hs[r2 + 32][col + j] = h1[nc][j] + bb;
    }
  }
  __syncthreads();

  // ---- gate & value: glu = sigmoid(h2@Wg+bg) * (h2@Wv+bv) → Hs ----
  float g0[5][4], g1[5][4], w0[5][4], w1[5][4];
#pragma unroll
  for (int nc = 0; nc < 5; ++nc)
#pragma unroll
    for (int j = 0; j < 4; ++j) { g0[nc][j] = g1[nc][j] = w0[nc][j] = w1[nc][j] = 0.f; }

  for (int nc = 0; nc < 5; ++nc) {
    stage_w32(Ws, sWg + wvoff, nc, tid);
    __syncthreads();
    gemm_pass(Hs, Ws, r2, cg, g0[nc], g1[nc]);
    __syncthreads();
    stage_w32(Ws, sWv + wvoff, nc, tid);
    __syncthreads();
    gemm_pass(Hs, Ws, r2, cg, w0[nc], w1[nc]);
    __syncthreads();
  }
#pragma unroll
  for (int nc = 0; nc < 5; ++nc) {
    const int col = nc * 32 + cg * 4;
#pragma unroll
    for (int j = 0; j < 4; ++j) {
      float bg = sbg[v * 160 + col + j];
      float bv = sbv[v * 160 + col + j];
      Hs[r2][col + j]      = sigmf(g0[nc][j] + bg) * (w0[nc][j] + bv);
      Hs[r2 + 32][col + j] = sigmf(g1[nc][j] + bg) * (w1[nc][j] + bv);
    }
  }
  __syncthreads();

  // ---- LayerNorm over h of (x + glu), then write bf16 transformed slab ----
  if (tid < 64) {
    float s = 0.f, s2 = 0.f;
    for (int h = 0; h < 160; ++h) {
      float y = Xs[tid][h] + Hs[tid][h];
      s += y; s2 += y * y;
    }
    float m   = s * (1.f / 160.f);
    float var = s2 * (1.f / 160.f) - m * m;
    redm[tid] = m;
    redr[tid] = 1.f / sqrtf(var + LNEPS);
  }
  __syncthreads();

  __hip_bfloat16* outp = trws + ((size_t)v * NBT + row0) * 160;
  for (int i = tid; i < 64 * 160; i += 256) {
    int r = i / 160, h = i - r * 160;
    float y = Xs[r][h] + Hs[r][h];
    float t = (y - redm[r]) * redr[r] * slns[v * 160 + h] + slnb[v * 160 + h];
    outp[i] = __float2bfloat16(t);
  }
}

// ---------------- Kernel 2: flattened GRN + softmax + weighted sum ----------------
// grid 512 row tiles, block 256
__global__ __launch_bounds__(256) void k_flat(
    const __hip_bfloat16* __restrict__ trws,
    const float* __restrict__ W1p, const float* __restrict__ Wskp,
    const float* __restrict__ ctxw,
    const float* __restrict__ fbskip,
    const float* __restrict__ fb1,
    const float* __restrict__ fW2, const float* __restrict__ fb2,
    const float* __restrict__ fWg, const float* __restrict__ fbg,
    const float* __restrict__ fWv, const float* __restrict__ fbv,
    const float* __restrict__ flns, const float* __restrict__ flnb,
    float* __restrict__ out)
{
  __shared__ __align__(16) float As[64][161];
  __shared__ __align__(16) float Ws[160][36];
  __shared__ float Ss[64][17];

  const int tid  = threadIdx.x;
  const int row0 = blockIdx.x * 64;
  const int b    = row0 >> 9;           // batch index (T=512, tile never crosses b)
  const int r2 = tid & 31, cg = tid >> 5;

  float acc0[5][4], acc1[5][4];      // h1 accumulator (flat @ fl_W1), cols nc*32+cg*4+j
  float sk0[4], sk1[4];              // skip accumulator (cg<4 threads own cols cg*4+j)
#pragma unroll
  for (int nc = 0; nc < 5; ++nc)
#pragma unroll
    for (int j = 0; j < 4; ++j) { acc0[nc][j] = acc1[nc][j] = 0.f; }
#pragma unroll
  for (int j = 0; j < 4; ++j) { sk0[j] = sk1[j] = 0.f; }

  // ---- K=2560 GEMMs streamed per-variable slab ----
  for (int v = 0; v < 16; ++v) {
    for (int i = tid; i < 64 * 160; i += 256) {
      int r = i / 160, h = i - r * 160;
      As[r][h] = __bfloat162float(trws[((size_t)v * NBT + row0 + r) * 160 + h]);
    }
    __syncthreads();

    const float* Wv1 = W1p + (size_t)v * 160 * 160;
    for (int nc = 0; nc < 5; ++nc) {
      stage_w32(Ws, Wv1, nc, tid);
      __syncthreads();
      gemm_pass(As, Ws, r2, cg, acc0[nc], acc1[nc]);
      __syncthreads();
    }
    // skip chunk: 16 cols
    for (int i = tid; i < 160 * 16; i += 256) {
      int k = i >> 4, j = i & 15;
      Ws[k][j] = Wskp[(size_t)v * 2560 + i];
    }
    __syncthreads();
    if (cg < 4) {
#pragma unroll 4
      for (int k = 0; k < 160; ++k) {
        float x0 = As[r2][k], x1 = As[r2 + 32][k];
        const float4 bq = *(const float4*)&Ws[k][cg * 4];
        sk0[0] += x0 * bq.x; sk0[1] += x0 * bq.y; sk0[2] += x0 * bq.z; sk0[3] += x0 * bq.w;
        sk1[0] += x1 * bq.x; sk1[1] += x1 * bq.y; sk1[2] += x1 * bq.z; sk1[3] += x1 * bq.w;
      }
    }
    __syncthreads();
  }

  // ---- h2a = elu(h1 + b1 + ctx) → As; skip (+bias) → Ss ----
#pragma unroll
  for (int nc = 0; nc < 5; ++nc) {
    const int col = nc * 32 + cg * 4;
#pragma unroll
    for (int j = 0; j < 4; ++j) {
      float add = fb1[col + j] + ctxw[b * 160 + col + j];
      As[r2][col + j]      = eluf(acc0[nc][j] + add);
      As[r2 + 32][col + j] = eluf(acc1[nc][j] + add);
    }
  }
  if (cg < 4) {
#pragma unroll
    for (int j = 0; j < 4; ++j) {
      Ss[r2][cg * 4 + j]      = sk0[j] + fbskip[cg * 4 + j];
      Ss[r2 + 32][cg * 4 + j] = sk1[j] + fbskip[cg * 4 + j];
    }
  }
  __syncthreads();

  // ---- h2b = h2a @ fl_W2 + b2 → As ----
#pragma unroll
  for (int nc = 0; nc < 5; ++nc)
#pragma unroll
    for (int j = 0; j < 4; ++j) { acc0[nc][j] = acc1[nc][j] = 0.f; }
  for (int nc = 0; nc < 5; ++nc) {
    stage_w32(Ws, fW2, nc, tid);
    __syncthreads();
    gemm_pass(As, Ws, r2, cg, acc0[nc], acc1[nc]);
    __syncthreads();
  }
#pragma unroll
  for (int nc = 0; nc < 5; ++nc) {
    const int col = nc * 32 + cg * 4;
#pragma unroll
    for (int j = 0; j < 4; ++j) {
      As[r2][col + j]      = acc0[nc][j] + fb2[col + j];
      As[r2 + 32][col + j] = acc1[nc][j] + fb2[col + j];
    }
  }
  __syncthreads();

  // ---- gate / value (N=16 each), outputs + pre-LN y → Ss ----
  for (int i = tid; i < 160 * 16; i += 256) {
    int k = i >> 4, j = i & 15;
    Ws[k][j]      = fWg[i];
    Ws[k][16 + j] = fWv[i];
  }
  __syncthreads();
  {
    const int rr = tid & 63, q = tid >> 6;   // row, col-quad
    float ga[4] = {0, 0, 0, 0}, va[4] = {0, 0, 0, 0};
#pragma unroll 4
    for (int k = 0; k < 160; ++k) {
      float a = As[rr][k];
      const float4 g4 = *(const float4*)&Ws[k][q * 4];
      const float4 v4 = *(const float4*)&Ws[k][16 + q * 4];
      ga[0] += a * g4.x; ga[1] += a * g4.y; ga[2] += a * g4.z; ga[3] += a * g4.w;
      va[0] += a * v4.x; va[1] += a * v4.y; va[2] += a * v4.z; va[3] += a * v4.w;
    }
#pragma unroll
    for (int j = 0; j < 4; ++j) {
      int jj = q * 4 + j;
      float g = sigmf(ga[j] + fbg[jj]);
      out[SG_OFF + (size_t)(row0 + rr) * 16 + jj] = g;           // static_gate
      float glu2 = g * (va[j] + fbv[jj]);
      float y = Ss[rr][jj] + glu2;                               // skip + glu2
      Ss[rr][jj] = y;
    }
  }
  __syncthreads();

  // ---- LN over 16 + softmax → sparse_weights out, sw → Ss ----
  if (tid < 64) {
    const int r = tid;
    float s = 0.f, s2 = 0.f;
#pragma unroll
    for (int j = 0; j < 16; ++j) { float t = Ss[r][j]; s += t; s2 += t * t; }
    float m   = s * (1.f / 16.f);
    float var = s2 * (1.f / 16.f) - m * m;
    float rstd = 1.f / sqrtf(var + LNEPS);
    float l[16], mx = -1e30f;
#pragma unroll
    for (int j = 0; j < 16; ++j) {
      l[j] = (Ss[r][j] - m) * rstd * flns[j] + flnb[j];
      mx = fmaxf(mx, l[j]);
    }
    float se = 0.f;
#pragma unroll
    for (int j = 0; j < 16; ++j) { l[j] = expf(l[j] - mx); se += l[j]; }
    float inv = 1.f / se;
#pragma unroll
    for (int j = 0; j < 16; ++j) {
      float sw = l[j] * inv;
      out[SW_OFF + (size_t)(row0 + r) * 16 + j] = sw;            // sparse_weights
      Ss[r][j] = sw;
    }
  }
  __syncthreads();

  // ---- temporal_ctx = sum_v transformed[v] * sw[v] ----
  float tc0[20], tc1[20];
#pragma unroll
  for (int j = 0; j < 20; ++j) { tc0[j] = tc1[j] = 0.f; }
  for (int v = 0; v < 16; ++v) {
    for (int i = tid; i < 64 * 160; i += 256) {
      int r = i / 160, h = i - r * 160;
      As[r][h] = __bfloat162float(trws[((size_t)v * NBT + row0 + r) * 160 + h]);
    }
    __syncthreads();
    float s0 = Ss[r2][v], s1 = Ss[r2 + 32][v];
#pragma unroll
    for (int j = 0; j < 20; ++j) {
      tc0[j] += As[r2][cg * 20 + j] * s0;
      tc1[j] += As[r2 + 32][cg * 20 + j] * s1;
    }
    __syncthreads();
  }
#pragma unroll
  for (int j = 0; j < 20; ++j) {
    out[TC_OFF + (size_t)(row0 + r2) * 160 + cg * 20 + j]        = tc0[j];
    out[TC_OFF + (size_t)(row0 + r2 + 32) * 160 + cg * 20 + j]   = tc1[j];
  }
}

// ---------------- small prep kernels ----------------
__global__ __launch_bounds__(256) void k_perm(const float* __restrict__ fW1,
                                              const float* __restrict__ fWsk,
                                              float* __restrict__ W1p,
                                              float* __restrict__ Wskp)
{
  int idx = blockIdx.x * 256 + threadIdx.x;
  if (idx < 409600) {            // W1p[(v*160+h)*160+c] = fW1[(h*16+v)*160+c]
    int c = idx % 160, rest = idx / 160;
    int v = rest / 160, h = rest - v * 160;
    W1p[idx] = fW1[(size_t)(h * 16 + v) * 160 + c];
  }
  if (idx < 40960) {             // Wskp[(v*160+h)*16+j] = fWsk[(h*16+v)*16+j]
    int j = idx & 15, rest = idx >> 4;
    int v = rest / 160, h = rest - v * 160;
    Wskp[idx] = fWsk[(size_t)(h * 16 + v) * 16 + j];
  }
}

__global__ __launch_bounds__(256) void k_ctx(const float* __restrict__ ac,
                                             const float* __restrict__ fWc,
                                             float* __restrict__ ctxw)
{
  int b = blockIdx.x, c = threadIdx.x;
  if (c < 160) {
    float s = 0.f;
    for (int k = 0; k < 160; ++k) s += ac[b * 160 + k] * fWc[k * 160 + c];
    ctxw[b * 160 + c] = s;
  }
}

extern "C" void kernel_launch(void* const* d_in, const int* in_sizes, int n_in,
                              void* d_out, int out_size, void* d_ws, size_t ws_size,
                              hipStream_t stream)
{
  const float* emb    = (const float*)d_in[0];
  const float* ac     = (const float*)d_in[1];
  const float* sW1    = (const float*)d_in[2];
  const float* sb1    = (const float*)d_in[3];
  const float* sW2    = (const float*)d_in[4];
  const float* sb2    = (const float*)d_in[5];
  const float* sWg    = (const float*)d_in[6];
  const float* sbg    = (const float*)d_in[7];
  const float* sWv    = (const float*)d_in[8];
  const float* sbv    = (const float*)d_in[9];
  const float* slns   = (const float*)d_in[10];
  const float* slnb   = (const float*)d_in[11];
  const float* fWskip = (const float*)d_in[12];
  const float* fbskip = (const float*)d_in[13];
  const float* fW1    = (const float*)d_in[14];
  const float* fb1    = (const float*)d_in[15];
  const float* fWc    = (const float*)d_in[16];
  const float* fW2    = (const float*)d_in[17];
  const float* fb2    = (const float*)d_in[18];
  const float* fWg    = (const float*)d_in[19];
  const float* fbg    = (const float*)d_in[20];
  const float* fWv    = (const float*)d_in[21];
  const float* fbv    = (const float*)d_in[22];
  const float* flns   = (const float*)d_in[23];
  const float* flnb   = (const float*)d_in[24];

  char* ws = (char*)d_ws;
  __hip_bfloat16* trws = (__hip_bfloat16*)ws;
  float* W1p  = (float*)(ws + WS_W1P_OFF);
  float* Wskp = (float*)(ws + WS_WSKP_OFF);
  float* ctxw = (float*)(ws + WS_CTX_OFF);
  float* out  = (float*)d_out;

  hipLaunchKernelGGL(k_perm, dim3(1600), dim3(256), 0, stream, fW1, fWskip, W1p, Wskp);
  hipLaunchKernelGGL(k_ctx,  dim3(64),   dim3(256), 0, stream, ac, fWc, ctxw);
  hipLaunchKernelGGL(k_var_grn, dim3(16, 512), dim3(256), 0, stream,
                     emb, sW1, sb1, sW2, sb2, sWg, sbg, sWv, sbv, slns, slnb, trws);
  hipLaunchKernelGGL(k_flat, dim3(512), dim3(256), 0, stream,
                     trws, W1p, Wskp, ctxw, fbskip, fb1, fW2, fb2,
                     fWg, fbg, fWv, fbv, flns, flnb, out);
}

// Round 5
// 1665.878 us; speedup vs baseline: 3.5090x; 3.5090x over previous
//
#include <hip/hip_runtime.h>

typedef __attribute__((ext_vector_type(8))) short bf16x8;
typedef __attribute__((ext_vector_type(4))) float f32x4;
typedef __attribute__((ext_vector_type(8))) unsigned short u16x8;
typedef unsigned short u16;

#define NBT 32768
#define TC_OFF 0ull
#define SW_OFF 5242880ull
#define SG_OFF 5767168ull

// workspace layout (bytes)
// trws  bf16 [V][BT][H]            : 167,772,160
// Wtg   bf16 [v][4][n][k]          :   3,276,800   (per-var W1,W2,Wg,Wv transposed)
// W1pt  bf16 [v][n][h]             :     819,200
// Wskpt bf16 [v][n<16][h]          :      81,920
// W2t   bf16 [n][k]                :      51,200
// Wgt   bf16 [n<16][k]             :       5,120
// Wvt   bf16 [n<16][k]             :       5,120
// ctxw  f32  [B][H]                :      40,960
#define WS_WTG   167772160ull
#define WS_W1PT  (WS_WTG   + 3276800ull)
#define WS_WSKPT (WS_W1PT  + 819200ull)
#define WS_W2T   (WS_WSKPT + 81920ull)
#define WS_WGT   (WS_W2T   + 51200ull)
#define WS_WVT   (WS_WGT   + 5120ull)
#define WS_CTX   (WS_WVT   + 5120ull)

__device__ __forceinline__ u16 f2bf(float f) {
  union { float f; unsigned u; } x; x.f = f;
  unsigned r = x.u + 0x7fffu + ((x.u >> 16) & 1u);
  return (u16)(r >> 16);
}
__device__ __forceinline__ float bf2f(u16 s) {
  union { unsigned u; float f; } x; x.u = ((unsigned)s) << 16; return x.f;
}
__device__ __forceinline__ float eluf(float x)  { return x > 0.f ? x : expm1f(x); }
__device__ __forceinline__ float sigmf(float x) { return 1.f / (1.f + expf(-x)); }

// stage a [160][160] bf16 global matrix into LDS [160][168] (row pad 8)
__device__ __forceinline__ void stage_wt(u16* W, const u16* __restrict__ src, int tid) {
  for (int i = tid; i < 160 * 20; i += 256) {
    int n = i / 20, c = i - n * 20;
    *(uint4*)&W[n * 168 + c * 8] = *(const uint4*)&src[n * 160 + c * 8];
  }
}

// 32-row x 80-col wave GEMM over K=160. A: LDS [*][168] rows wr0..wr0+31.
// B: LDS [n][168] cols wc0..wc0+79 (B stored transposed: Bw[n][k]).
__device__ __forceinline__ void mm_5(const u16* Ab, const u16* Bw, int wr0, int wc0,
                                     int lane, f32x4 acc[2][5]) {
  const int kl = (lane >> 4) << 3;
  const int lc = lane & 15;
#pragma unroll
  for (int k0 = 0; k0 < 160; k0 += 32) {
    bf16x8 a0 = *(const bf16x8*)&Ab[(wr0 + lc) * 168 + k0 + kl];
    bf16x8 a1 = *(const bf16x8*)&Ab[(wr0 + 16 + lc) * 168 + k0 + kl];
#pragma unroll
    for (int nf = 0; nf < 5; ++nf) {
      bf16x8 b = *(const bf16x8*)&Bw[(wc0 + nf * 16 + lc) * 168 + k0 + kl];
      acc[0][nf] = __builtin_amdgcn_mfma_f32_16x16x32_bf16(a0, b, acc[0][nf], 0, 0, 0);
      acc[1][nf] = __builtin_amdgcn_mfma_f32_16x16x32_bf16(a1, b, acc[1][nf], 0, 0, 0);
    }
  }
}

// 32-row x 16-col wave GEMM over K=160 (N=16 tail). Bw: LDS [16][168].
__device__ __forceinline__ void mm_1(const u16* Ab, const u16* Bw, int wr0,
                                     int lane, f32x4 acc[2]) {
  const int kl = (lane >> 4) << 3;
  const int lc = lane & 15;
#pragma unroll
  for (int k0 = 0; k0 < 160; k0 += 32) {
    bf16x8 a0 = *(const bf16x8*)&Ab[(wr0 + lc) * 168 + k0 + kl];
    bf16x8 a1 = *(const bf16x8*)&Ab[(wr0 + 16 + lc) * 168 + k0 + kl];
    bf16x8 b  = *(const bf16x8*)&Bw[lc * 168 + k0 + kl];
    acc[0] = __builtin_amdgcn_mfma_f32_16x16x32_bf16(a0, b, acc[0], 0, 0, 0);
    acc[1] = __builtin_amdgcn_mfma_f32_16x16x32_bf16(a1, b, acc[1], 0, 0, 0);
  }
}

// ---------------- prep: per-variable weights -> transposed bf16 ----------------
// Wtg[((v*4+s)*160+n)*160+k] = bf16(W_s[v][k][n]); grid 16*4*25 blocks x 256
__global__ __launch_bounds__(256) void k_prep_wvar(
    const float* __restrict__ sW1, const float* __restrict__ sW2,
    const float* __restrict__ sWg, const float* __restrict__ sWv,
    u16* __restrict__ Wtg) {
  const float* srcs[4] = { sW1, sW2, sWg, sWv };
  int b = blockIdx.x;
  int vs = b / 25, t = b - vs * 25;
  int v = vs >> 2, s = vs & 3;
  const float* src = srcs[s] + (size_t)v * 25600;
  int k0 = (t / 5) * 32, n0 = (t % 5) * 32;
  __shared__ float tile_[32][33];
  int r = threadIdx.x >> 5, c = threadIdx.x & 31;
  for (int rr = r; rr < 32; rr += 8) tile_[rr][c] = src[(size_t)(k0 + rr) * 160 + n0 + c];
  __syncthreads();
  u16* dst = Wtg + (size_t)vs * 25600;
  for (int rr = r; rr < 32; rr += 8) dst[(size_t)(n0 + rr) * 160 + k0 + c] = f2bf(tile_[c][rr]);
}

// W1pt[v][n][h] = bf16(fl_W1[(h*16+v)*160+n]); grid 16*25 blocks x 256
__global__ __launch_bounds__(256) void k_prep_w1pt(const float* __restrict__ fW1,
                                                   u16* __restrict__ W1pt) {
  int b = blockIdx.x;
  int v = b / 25, t = b - v * 25;
  int h0 = (t / 5) * 32, n0 = (t % 5) * 32;
  __shared__ float tile_[32][33];
  int r = threadIdx.x >> 5, c = threadIdx.x & 31;
  for (int rr = r; rr < 32; rr += 8)
    tile_[rr][c] = fW1[(size_t)(h0 + rr) * 2560 + v * 160 + n0 + c];
  __syncthreads();
  u16* dst = W1pt + (size_t)v * 25600;
  for (int rr = r; rr < 32; rr += 8) dst[(size_t)(n0 + rr) * 160 + h0 + c] = f2bf(tile_[c][rr]);
}

// small tails: Wskpt, W2t, Wgt, Wvt ; 71680 elements
__global__ __launch_bounds__(256) void k_prep_small(
    const float* __restrict__ fWskip, const float* __restrict__ fW2,
    const float* __restrict__ fWg, const float* __restrict__ fWv,
    u16* __restrict__ Wskpt, u16* __restrict__ W2t,
    u16* __restrict__ Wgt, u16* __restrict__ Wvt) {
  int idx = blockIdx.x * 256 + threadIdx.x;
  if (idx < 40960) {                       // Wskpt[(v*16+n)*160+h] = fl_Wskip[(h*16+v)*16+n]
    int h = idx % 160, rest = idx / 160;
    int n = rest & 15, v = rest >> 4;
    Wskpt[idx] = f2bf(fWskip[(size_t)(h * 16 + v) * 16 + n]);
  } else if (idx < 66560) {                // W2t[n*160+k] = fl_W2[k*160+n]
    int i2 = idx - 40960;
    int k = i2 % 160, n = i2 / 160;
    W2t[i2] = f2bf(fW2[(size_t)k * 160 + n]);
  } else if (idx < 69120) {                // Wgt[n*160+k] = fl_Wg[k*16+n]
    int i3 = idx - 66560;
    int k = i3 % 160, n = i3 / 160;
    Wgt[i3] = f2bf(fWg[(size_t)k * 16 + n]);
  } else if (idx < 71680) {                // Wvt[n*160+k] = fl_Wv[k*16+n]
    int i4 = idx - 69120;
    int k = i4 % 160, n = i4 / 160;
    Wvt[i4] = f2bf(fWv[(size_t)k * 16 + n]);
  }
}

__global__ __launch_bounds__(256) void k_ctx(const float* __restrict__ ac,
                                             const float* __restrict__ fWc,
                                             float* __restrict__ ctxw) {
  int b = blockIdx.x, c = threadIdx.x;
  if (c < 160) {
    float s = 0.f;
    for (int k = 0; k < 160; ++k) s += ac[b * 160 + k] * fWc[k * 160 + c];
    ctxw[b * 160 + c] = s;
  }
}

// ---------------- Kernel 1: per-variable GRN (MFMA) ----------------
// grid 8192 blocks (XCD-swizzled (v,tile)), block 256 = 4 waves (2Mx2N)
__global__ __launch_bounds__(256, 2) void k_var_grn(
    const float* __restrict__ emb, const u16* __restrict__ Wtg,
    const float* __restrict__ sb1, const float* __restrict__ sb2,
    const float* __restrict__ sbg, const float* __restrict__ sbv,
    const float* __restrict__ slns, const float* __restrict__ slnb,
    u16* __restrict__ trws) {
  __shared__ __align__(16) u16 Abuf[64 * 168];
  __shared__ __align__(16) u16 Wt[160 * 168];
  __shared__ float red[2 * 64 * 2];

  const int tid = threadIdx.x;
  const int bid = blockIdx.x;
  // 16 v-blocks of one tile land on the same XCD (assuming xcd = bid & 7)
  const int slot = bid >> 3, xcd = bid & 7;
  const int tile = xcd * 64 + (slot >> 4);
  const int v = slot & 15;
  const int row0 = tile * 64;

  const int lane = tid & 63, wave = tid >> 6;
  const int wr0 = (wave & 1) * 32;         // row-half
  const int ch  = wave >> 1;               // col-half
  const int wc0 = ch * 80;
  const int lrow = (lane >> 4) << 2;
  const int lc = lane & 15;

  float b1c[5], b2c[5], bgc[5], bvc[5], lsc[5], lbc[5];
#pragma unroll
  for (int nf = 0; nf < 5; ++nf) {
    int col = v * 160 + wc0 + nf * 16 + lc;
    b1c[nf] = sb1[col]; b2c[nf] = sb2[col];
    bgc[nf] = sbg[col]; bvc[nf] = sbv[col];
    lsc[nf] = slns[col]; lbc[nf] = slnb[col];
  }

  // stage X -> Abuf bf16 (strided fp32 global reads; lines L2-shared across v-blocks)
  for (int i = tid; i < 64 * 160; i += 256) {
    int r = i / 160, e = i - r * 160;
    Abuf[r * 168 + e] = f2bf(emb[(size_t)(row0 + r) * 2560 + e * 16 + v]);
  }
  const u16* wbase = Wtg + (size_t)(v * 4) * 25600;
  stage_wt(Wt, wbase, tid);                       // W1^T
  __syncthreads();

  // ---- h1 = elu(X @ W1 + b1) ----
  f32x4 acc[2][5];
#pragma unroll
  for (int fr = 0; fr < 2; ++fr)
#pragma unroll
    for (int nf = 0; nf < 5; ++nf) acc[fr][nf] = (f32x4){0.f, 0.f, 0.f, 0.f};
  mm_5(Abuf, Wt, wr0, wc0, lane, acc);
  __syncthreads();
#pragma unroll
  for (int fr = 0; fr < 2; ++fr)
#pragma unroll
    for (int nf = 0; nf < 5; ++nf)
#pragma unroll
      for (int r = 0; r < 4; ++r)
        Abuf[(wr0 + fr * 16 + lrow + r) * 168 + wc0 + nf * 16 + lc] =
            f2bf(eluf(acc[fr][nf][r] + b1c[nf]));
  stage_wt(Wt, wbase + 25600, tid);               // W2^T
  __syncthreads();

  // ---- h2 = h1 @ W2 + b2 ----
#pragma unroll
  for (int fr = 0; fr < 2; ++fr)
#pragma unroll
    for (int nf = 0; nf < 5; ++nf) acc[fr][nf] = (f32x4){0.f, 0.f, 0.f, 0.f};
  mm_5(Abuf, Wt, wr0, wc0, lane, acc);
  __syncthreads();
  float xr[2][5][4];
#pragma unroll
  for (int fr = 0; fr < 2; ++fr)
#pragma unroll
    for (int nf = 0; nf < 5; ++nf)
#pragma unroll
      for (int r = 0; r < 4; ++r) {
        Abuf[(wr0 + fr * 16 + lrow + r) * 168 + wc0 + nf * 16 + lc] =
            f2bf(acc[fr][nf][r] + b2c[nf]);
        // prefetch x (fp32, L2-warm) in D-fragment layout for the skip/LN path
        xr[fr][nf][r] = emb[(size_t)(row0 + wr0 + fr * 16 + lrow + r) * 2560 +
                            (wc0 + nf * 16 + lc) * 16 + v];
      }
  stage_wt(Wt, wbase + 51200, tid);               // Wg^T
  __syncthreads();

  // ---- gate / value GEMMs ----
  f32x4 gacc[2][5];
#pragma unroll
  for (int fr = 0; fr < 2; ++fr)
#pragma unroll
    for (int nf = 0; nf < 5; ++nf) gacc[fr][nf] = (f32x4){0.f, 0.f, 0.f, 0.f};
  mm_5(Abuf, Wt, wr0, wc0, lane, gacc);
  __syncthreads();
  stage_wt(Wt, wbase + 76800, tid);               // Wv^T
  __syncthreads();
  f32x4 vacc[2][5];
#pragma unroll
  for (int fr = 0; fr < 2; ++fr)
#pragma unroll
    for (int nf = 0; nf < 5; ++nf) vacc[fr][nf] = (f32x4){0.f, 0.f, 0.f, 0.f};
  mm_5(Abuf, Wt, wr0, wc0, lane, vacc);

  // ---- y = x + sigm(g+bg)*(v+bv); LN partials ----
  float yv[2][5][4];
#pragma unroll
  for (int fr = 0; fr < 2; ++fr)
#pragma unroll
    for (int nf = 0; nf < 5; ++nf)
#pragma unroll
      for (int r = 0; r < 4; ++r)
        yv[fr][nf][r] = xr[fr][nf][r] +
            sigmf(gacc[fr][nf][r] + bgc[nf]) * (vacc[fr][nf][r] + bvc[nf]);

#pragma unroll
  for (int fr = 0; fr < 2; ++fr)
#pragma unroll
    for (int r = 0; r < 4; ++r) {
      float s = 0.f, s2 = 0.f;
#pragma unroll
      for (int nf = 0; nf < 5; ++nf) { float y = yv[fr][nf][r]; s += y; s2 += y * y; }
#pragma unroll
      for (int m = 1; m < 16; m <<= 1) {
        s += __shfl_xor(s, m, 64); s2 += __shfl_xor(s2, m, 64);
      }
      if (lc == 0) {
        int row = wr0 + fr * 16 + lrow + r;
        red[(ch * 64 + row) * 2]     = s;
        red[(ch * 64 + row) * 2 + 1] = s2;
      }
    }
  __syncthreads();

  // ---- finalize LN, write bf16 transformed into Abuf, then vector-store ----
#pragma unroll
  for (int fr = 0; fr < 2; ++fr)
#pragma unroll
    for (int r = 0; r < 4; ++r) {
      int row = wr0 + fr * 16 + lrow + r;
      float s  = red[row * 2]     + red[(64 + row) * 2];
      float s2 = red[row * 2 + 1] + red[(64 + row) * 2 + 1];
      float mn = s * (1.f / 160.f);
      float var = s2 * (1.f / 160.f) - mn * mn;
      float rstd = rsqrtf(var + 1e-5f);
#pragma unroll
      for (int nf = 0; nf < 5; ++nf) {
        float t = (yv[fr][nf][r] - mn) * rstd * lsc[nf] + lbc[nf];
        Abuf[row * 168 + wc0 + nf * 16 + lc] = f2bf(t);
      }
    }
  __syncthreads();
  for (int i = tid; i < 64 * 20; i += 256) {
    int r = i / 20, c = i - r * 20;
    *(uint4*)&trws[((size_t)v * NBT + row0 + r) * 160 + c * 8] =
        *(const uint4*)&Abuf[r * 168 + c * 8];
  }
}

// ---------------- Kernel 2: flattened GRN + softmax + weighted sum ----------------
// grid 512, block 256
__global__ __launch_bounds__(256, 2) void k_flat(
    const u16* __restrict__ trws, const u16* __restrict__ W1pt,
    const u16* __restrict__ Wskpt, const u16* __restrict__ W2t,
    const u16* __restrict__ Wgt, const u16* __restrict__ Wvt,
    const float* __restrict__ ctxw,
    const float* __restrict__ fbskip, const float* __restrict__ fb1,
    const float* __restrict__ fb2, const float* __restrict__ fbg,
    const float* __restrict__ fbv, const float* __restrict__ flns,
    const float* __restrict__ flnb, float* __restrict__ out) {
  __shared__ __align__(16) u16 Abuf[64 * 168];
  __shared__ __align__(16) u16 Wt[160 * 168];
  __shared__ __align__(16) u16 Wsk[32 * 168];
  __shared__ float Ss[64 * 17];

  const int tid = threadIdx.x;
  const int row0 = blockIdx.x * 64;
  const int b = row0 >> 9;

  const int lane = tid & 63, wave = tid >> 6;
  const int wr0 = (wave & 1) * 32;
  const int ch  = wave >> 1;
  const int wc0 = ch * 80;
  const int lrow = (lane >> 4) << 2;
  const int lc = lane & 15;

  f32x4 acc[2][5];
#pragma unroll
  for (int fr = 0; fr < 2; ++fr)
#pragma unroll
    for (int nf = 0; nf < 5; ++nf) acc[fr][nf] = (f32x4){0.f, 0.f, 0.f, 0.f};
  f32x4 skp[2] = { (f32x4){0.f,0.f,0.f,0.f}, (f32x4){0.f,0.f,0.f,0.f} };

  // ---- h1 = flat @ fl_W1 (K=2560 streamed per-variable); skip = flat @ fl_Wskip ----
  for (int v = 0; v < 16; ++v) {
    const u16* trg = trws + (size_t)v * NBT * 160;
    for (int i = tid; i < 64 * 20; i += 256) {
      int r = i / 20, c = i - r * 20;
      *(uint4*)&Abuf[r * 168 + c * 8] = *(const uint4*)&trg[(size_t)(row0 + r) * 160 + c * 8];
    }
    stage_wt(Wt, W1pt + (size_t)v * 25600, tid);
    for (int i = tid; i < 16 * 20; i += 256) {
      int n = i / 20, c = i - n * 20;
      *(uint4*)&Wsk[n * 168 + c * 8] = *(const uint4*)&Wskpt[(size_t)v * 2560 + n * 160 + c * 8];
    }
    __syncthreads();
    mm_5(Abuf, Wt, wr0, wc0, lane, acc);
    if (ch == 0) mm_1(Abuf, Wsk, wr0, lane, skp);
    __syncthreads();
  }

  // ---- h2a = elu(h1 + b1 + ctx) ----
  float ctxc[5], b1c[5], b2c[5];
#pragma unroll
  for (int nf = 0; nf < 5; ++nf) {
    int col = wc0 + nf * 16 + lc;
    ctxc[nf] = ctxw[b * 160 + col];
    b1c[nf] = fb1[col]; b2c[nf] = fb2[col];
  }
#pragma unroll
  for (int fr = 0; fr < 2; ++fr)
#pragma unroll
    for (int nf = 0; nf < 5; ++nf)
#pragma unroll
      for (int r = 0; r < 4; ++r)
        Abuf[(wr0 + fr * 16 + lrow + r) * 168 + wc0 + nf * 16 + lc] =
            f2bf(eluf(acc[fr][nf][r] + b1c[nf] + ctxc[nf]));
  stage_wt(Wt, W2t, tid);
  for (int i = tid; i < 16 * 20; i += 256) {
    int n = i / 20, c = i - n * 20;
    *(uint4*)&Wsk[n * 168 + c * 8]        = *(const uint4*)&Wgt[n * 160 + c * 8];
  }
  for (int i = tid; i < 16 * 20; i += 256) {
    int n = i / 20, c = i - n * 20;
    *(uint4*)&Wsk[(16 + n) * 168 + c * 8] = *(const uint4*)&Wvt[n * 160 + c * 8];
  }
  __syncthreads();

  // ---- h2b = h2a @ fl_W2 + b2 ----
#pragma unroll
  for (int fr = 0; fr < 2; ++fr)
#pragma unroll
    for (int nf = 0; nf < 5; ++nf) acc[fr][nf] = (f32x4){0.f, 0.f, 0.f, 0.f};
  mm_5(Abuf, Wt, wr0, wc0, lane, acc);
  __syncthreads();
#pragma unroll
  for (int fr = 0; fr < 2; ++fr)
#pragma unroll
    for (int nf = 0; nf < 5; ++nf)
#pragma unroll
      for (int r = 0; r < 4; ++r)
        Abuf[(wr0 + fr * 16 + lrow + r) * 168 + wc0 + nf * 16 + lc] =
            f2bf(acc[fr][nf][r] + b2c[nf]);
  __syncthreads();

  // ---- gate/value tails, LN(16), softmax, outputs ----
  if (ch == 0) {
    f32x4 ga[2] = { (f32x4){0.f,0.f,0.f,0.f}, (f32x4){0.f,0.f,0.f,0.f} };
    f32x4 va[2] = { (f32x4){0.f,0.f,0.f,0.f}, (f32x4){0.f,0.f,0.f,0.f} };
    mm_1(Abuf, Wsk, wr0, lane, ga);
    mm_1(Abuf, Wsk + 16 * 168, wr0, lane, va);
    float bg_ = fbg[lc], bv_ = fbv[lc], bsk_ = fbskip[lc];
    float ls_ = flns[lc], lb_ = flnb[lc];
#pragma unroll
    for (int fr = 0; fr < 2; ++fr)
#pragma unroll
      for (int r = 0; r < 4; ++r) {
        int row = wr0 + fr * 16 + lrow + r;
        float g = sigmf(ga[fr][r] + bg_);
        out[SG_OFF + (size_t)(row0 + row) * 16 + lc] = g;
        float y = skp[fr][r] + bsk_ + g * (va[fr][r] + bv_);
        float s = y, s2 = y * y;
#pragma unroll
        for (int m = 1; m < 16; m <<= 1) {
          s += __shfl_xor(s, m, 64); s2 += __shfl_xor(s2, m, 64);
        }
        float mn = s * (1.f / 16.f);
        float var = s2 * (1.f / 16.f) - mn * mn;
        float t = (y - mn) * rsqrtf(var + 1e-5f) * ls_ + lb_;
        float mx = t;
#pragma unroll
        for (int m = 1; m < 16; m <<= 1) mx = fmaxf(mx, __shfl_xor(mx, m, 64));
        float e = expf(t - mx);
        float se = e;
#pragma unroll
        for (int m = 1; m < 16; m <<= 1) se += __shfl_xor(se, m, 64);
        float sw = e / se;
        out[SW_OFF + (size_t)(row0 + row) * 16 + lc] = sw;
        Ss[row * 17 + lc] = sw;
      }
  }
  __syncthreads();

  // ---- temporal_ctx = sum_v transformed[v] * sw[v] ----
  float tc[5][8];
#pragma unroll
  for (int j = 0; j < 5; ++j)
#pragma unroll
    for (int e = 0; e < 8; ++e) tc[j][e] = 0.f;
  for (int v = 0; v < 16; ++v) {
    const u16* trg = trws + (size_t)v * NBT * 160;
#pragma unroll
    for (int j = 0; j < 5; ++j) {
      int c = tid + j * 256;
      int row = c / 20, h0 = (c - row * 20) * 8;
      u16x8 d = *(const u16x8*)&trg[(size_t)(row0 + row) * 160 + h0];
      float w = Ss[row * 17 + v];
#pragma unroll
      for (int e = 0; e < 8; ++e) tc[j][e] += bf2f(d[e]) * w;
    }
  }
#pragma unroll
  for (int j = 0; j < 5; ++j) {
    int c = tid + j * 256;
    int row = c / 20, h0 = (c - row * 20) * 8;
    float4 o0 = { tc[j][0], tc[j][1], tc[j][2], tc[j][3] };
    float4 o1 = { tc[j][4], tc[j][5], tc[j][6], tc[j][7] };
    *(float4*)&out[TC_OFF + (size_t)(row0 + row) * 160 + h0]     = o0;
    *(float4*)&out[TC_OFF + (size_t)(row0 + row) * 160 + h0 + 4] = o1;
  }
}

extern "C" void kernel_launch(void* const* d_in, const int* in_sizes, int n_in,
                              void* d_out, int out_size, void* d_ws, size_t ws_size,
                              hipStream_t stream) {
  const float* emb    = (const float*)d_in[0];
  const float* ac     = (const float*)d_in[1];
  const float* sW1    = (const float*)d_in[2];
  const float* sb1    = (const float*)d_in[3];
  const float* sW2    = (const float*)d_in[4];
  const float* sb2    = (const float*)d_in[5];
  const float* sWg    = (const float*)d_in[6];
  const float* sbg    = (const float*)d_in[7];
  const float* sWv    = (const float*)d_in[8];
  const float* sbv    = (const float*)d_in[9];
  const float* slns   = (const float*)d_in[10];
  const float* slnb   = (const float*)d_in[11];
  const float* fWskip = (const float*)d_in[12];
  const float* fbskip = (const float*)d_in[13];
  const float* fW1    = (const float*)d_in[14];
  const float* fb1    = (const float*)d_in[15];
  const float* fWc    = (const float*)d_in[16];
  const float* fW2    = (const float*)d_in[17];
  const float* fb2    = (const float*)d_in[18];
  const float* fWg    = (const float*)d_in[19];
  const float* fbg    = (const float*)d_in[20];
  const float* fWv    = (const float*)d_in[21];
  const float* fbv    = (const float*)d_in[22];
  const float* flns   = (const float*)d_in[23];
  const float* flnb   = (const float*)d_in[24];

  char* ws = (char*)d_ws;
  u16* trws   = (u16*)ws;
  u16* Wtg    = (u16*)(ws + WS_WTG);
  u16* W1pt   = (u16*)(ws + WS_W1PT);
  u16* Wskpt  = (u16*)(ws + WS_WSKPT);
  u16* W2t    = (u16*)(ws + WS_W2T);
  u16* Wgt    = (u16*)(ws + WS_WGT);
  u16* Wvt    = (u16*)(ws + WS_WVT);
  float* ctxw = (float*)(ws + WS_CTX);
  float* out  = (float*)d_out;

  hipLaunchKernelGGL(k_prep_wvar, dim3(1600), dim3(256), 0, stream, sW1, sW2, sWg, sWv, Wtg);
  hipLaunchKernelGGL(k_prep_w1pt, dim3(400),  dim3(256), 0, stream, fW1, W1pt);
  hipLaunchKernelGGL(k_prep_small, dim3(280), dim3(256), 0, stream,
                     fWskip, fW2, fWg, fWv, Wskpt, W2t, Wgt, Wvt);
  hipLaunchKernelGGL(k_ctx, dim3(64), dim3(256), 0, stream, ac, fWc, ctxw);
  hipLaunchKernelGGL(k_var_grn, dim3(8192), dim3(256), 0, stream,
                     emb, Wtg, sb1, sb2, sbg, sbv, slns, slnb, trws);
  hipLaunchKernelGGL(k_flat, dim3(512), dim3(256), 0, stream,
                     trws, W1pt, Wskpt, W2t, Wgt, Wvt, ctxw,
                     fbskip, fb1, fb2, fbg, fbv, flns, flnb, out);
}